// Round 1
// baseline (2265.666 us; speedup 1.0000x reference)
//
#include <hip/hip_runtime.h>

// ---------------------------------------------------------------------------
// TorsoGCNv1: 3x GCNConv(+ReLU) -> global mean pool -> Linear head
//   x:[N,128] f32, edge_index:[2,E] int, batch:[N] int (sorted)
//   layer dims: 128->128->64->32, head 32->768, out [256,768] f32
// ---------------------------------------------------------------------------

__global__ void deg_kernel(const int* __restrict__ dst, float* __restrict__ deg, int E) {
    int e = blockIdx.x * blockDim.x + threadIdx.x;
    if (e < E) atomicAdd(&deg[dst[e]], 1.0f);
}

__global__ void dis_kernel(float* __restrict__ deg, int N) {
    int n = blockIdx.x * blockDim.x + threadIdx.x;
    if (n < N) deg[n] = rsqrtf(deg[n] + 1.0f);   // in-place: deg -> deg^{-1/2}
}

// h[n][c] = dis[n] * sum_k x[n][k] * W[k][c]
template <int K, int C>
__global__ void gemm_scale_kernel(const float* __restrict__ x, const float* __restrict__ W,
                                  const float* __restrict__ dis, float* __restrict__ h, int N) {
    constexpr int NPB = 256 / C;                 // nodes per block
    __shared__ float xs[NPB][K];
    const int local = threadIdx.x / C;
    const int c     = threadIdx.x % C;
    const int node  = blockIdx.x * NPB + local;

    for (int i = threadIdx.x; i < NPB * K; i += 256) {
        const int ln = i / K, kk = i % K;
        const int nn = blockIdx.x * NPB + ln;
        xs[ln][kk] = (nn < N) ? x[(size_t)nn * K + kk] : 0.0f;
    }
    __syncthreads();
    if (node >= N) return;

    float acc = 0.0f;
#pragma unroll 8
    for (int k = 0; k < K; ++k) acc = fmaf(xs[local][k], W[k * C + c], acc);
    h[(size_t)node * C + c] = acc * dis[node];
}

// agg[dst] += h[src]   (one thread per edge x 4-channel quad)
template <int C>
__global__ void scatter_kernel(const float* __restrict__ h, const int* __restrict__ src,
                               const int* __restrict__ dst, float* __restrict__ agg, int E) {
    constexpr int CQ = C / 4;
    const long long tid = (long long)blockIdx.x * blockDim.x + threadIdx.x;
    const int e = (int)(tid / CQ);
    const int q = (int)(tid % CQ);
    if (e >= E) return;
    const int s = src[e];
    const int d = dst[e];
    const float4 v = *reinterpret_cast<const float4*>(&h[(size_t)s * C + q * 4]);
    float* a = &agg[(size_t)d * C + q * 4];
    atomicAdd(a + 0, v.x);
    atomicAdd(a + 1, v.y);
    atomicAdd(a + 2, v.z);
    atomicAdd(a + 3, v.w);
}

// agg = relu((agg + h) * dis[n] + b[c])   (in place -> becomes next layer input)
template <int C>
__global__ void combine_kernel(const float* __restrict__ h, float* __restrict__ agg,
                               const float* __restrict__ dis, const float* __restrict__ b, int N) {
    const long long tid = (long long)blockIdx.x * blockDim.x + threadIdx.x;
    if (tid >= (long long)N * C) return;
    const int n = (int)(tid / C);
    const int c = (int)(tid % C);
    float v = (agg[tid] + h[tid]) * dis[n] + b[c];
    agg[tid] = v > 0.0f ? v : 0.0f;
}

__global__ void counts_kernel(const int* __restrict__ batch, float* __restrict__ counts, int N) {
    int n = blockIdx.x * blockDim.x + threadIdx.x;
    if (n < N) atomicAdd(&counts[batch[n]], 1.0f);
}

// pooled[batch[n]][c] += x3[n][c]   (C = 32)
__global__ void pool_kernel(const float* __restrict__ x3, const int* __restrict__ batch,
                            float* __restrict__ pooled, int N) {
    const long long tid = (long long)blockIdx.x * blockDim.x + threadIdx.x;
    if (tid >= (long long)N * 32) return;
    const int n = (int)(tid / 32);
    const int c = (int)(tid % 32);
    atomicAdd(&pooled[batch[n] * 32 + c], x3[tid]);
}

// out[g][j] = (pooled[g][:]/max(counts[g],1)) . Wl[:,j] + bl[j]
__global__ void head_kernel(const float* __restrict__ pooled, const float* __restrict__ counts,
                            const float* __restrict__ Wl, const float* __restrict__ bl,
                            float* __restrict__ out) {
    __shared__ float p[32];
    const int g = blockIdx.x;
    if (threadIdx.x < 32) {
        float cnt = counts[g];
        cnt = cnt < 1.0f ? 1.0f : cnt;
        p[threadIdx.x] = pooled[g * 32 + threadIdx.x] / cnt;
    }
    __syncthreads();
    const int j = threadIdx.x;  // blockDim.x == 768
    float acc = bl[j];
#pragma unroll
    for (int k = 0; k < 32; ++k) acc = fmaf(p[k], Wl[k * 768 + j], acc);
    out[g * 768 + j] = acc;
}

extern "C" void kernel_launch(void* const* d_in, const int* in_sizes, int n_in,
                              void* d_out, int out_size, void* d_ws, size_t ws_size,
                              hipStream_t stream) {
    const float* x   = (const float*)d_in[0];
    const float* W1  = (const float*)d_in[1];
    const float* b1  = (const float*)d_in[2];
    const float* W2  = (const float*)d_in[3];
    const float* b2  = (const float*)d_in[4];
    const float* W3  = (const float*)d_in[5];
    const float* b3  = (const float*)d_in[6];
    const float* Wl  = (const float*)d_in[7];
    const float* bl  = (const float*)d_in[8];
    const int* ei    = (const int*)d_in[9];
    const int* batch = (const int*)d_in[10];

    const int N = in_sizes[0] / 128;    // 40000
    const int E = in_sizes[9] / 2;      // 640000
    const int G = out_size / 768;       // 256

    const int* src = ei;
    const int* dst = ei + E;
    float* out = (float*)d_out;

    // Workspace layout (floats): P0[N*128] | P1[N*128] | H[N*128] | deg[N] | pooled[G*32] | counts[G]
    float* P0     = (float*)d_ws;
    float* P1     = P0 + (size_t)N * 128;
    float* H      = P1 + (size_t)N * 128;
    float* deg    = H + (size_t)N * 128;
    float* pooled = deg + N;
    float* counts = pooled + (size_t)G * 32;

    // degree (incl. self loop) -> deg^{-1/2}, stored in deg
    hipMemsetAsync(deg, 0, (size_t)N * sizeof(float), stream);
    hipMemsetAsync(pooled, 0, ((size_t)G * 32 + G) * sizeof(float), stream);
    deg_kernel<<<(E + 255) / 256, 256, 0, stream>>>(dst, deg, E);
    dis_kernel<<<(N + 255) / 256, 256, 0, stream>>>(deg, N);

    // ---- Layer 1: 128 -> 128 : x -> P0
    gemm_scale_kernel<128, 128><<<(N + 1) / 2, 256, 0, stream>>>(x, W1, deg, H, N);
    hipMemsetAsync(P0, 0, (size_t)N * 128 * sizeof(float), stream);
    scatter_kernel<128><<<(int)(((long long)E * 32 + 255) / 256), 256, 0, stream>>>(H, src, dst, P0, E);
    combine_kernel<128><<<(int)(((long long)N * 128 + 255) / 256), 256, 0, stream>>>(H, P0, deg, b1, N);

    // ---- Layer 2: 128 -> 64 : P0 -> P1
    gemm_scale_kernel<128, 64><<<(N + 3) / 4, 256, 0, stream>>>(P0, W2, deg, H, N);
    hipMemsetAsync(P1, 0, (size_t)N * 64 * sizeof(float), stream);
    scatter_kernel<64><<<(int)(((long long)E * 16 + 255) / 256), 256, 0, stream>>>(H, src, dst, P1, E);
    combine_kernel<64><<<(int)(((long long)N * 64 + 255) / 256), 256, 0, stream>>>(H, P1, deg, b2, N);

    // ---- Layer 3: 64 -> 32 : P1 -> P0
    gemm_scale_kernel<64, 32><<<(N + 7) / 8, 256, 0, stream>>>(P1, W3, deg, H, N);
    hipMemsetAsync(P0, 0, (size_t)N * 32 * sizeof(float), stream);
    scatter_kernel<32><<<(int)(((long long)E * 8 + 255) / 256), 256, 0, stream>>>(H, src, dst, P0, E);
    combine_kernel<32><<<(int)(((long long)N * 32 + 255) / 256), 256, 0, stream>>>(H, P0, deg, b3, N);

    // ---- Global mean pool + head
    counts_kernel<<<(N + 255) / 256, 256, 0, stream>>>(batch, counts, N);
    pool_kernel<<<(int)(((long long)N * 32 + 255) / 256), 256, 0, stream>>>(P0, batch, pooled, N);
    head_kernel<<<G, 768, 0, stream>>>(pooled, counts, Wl, bl, out);
}

// Round 2
// 486.196 us; speedup vs baseline: 4.6600x; 4.6600x over previous
//
#include <hip/hip_runtime.h>

// ---------------------------------------------------------------------------
// TorsoGCNv1: 3x GCNConv(+ReLU) -> global mean pool -> Linear head
// Round 2: CSR-by-dst gather (no float atomics), fused combine/bias/ReLU.
// ---------------------------------------------------------------------------

// ---- CSR build -------------------------------------------------------------

__global__ void deg_count_kernel(const int* __restrict__ dst, int* __restrict__ deg, int E) {
    int e = blockIdx.x * blockDim.x + threadIdx.x;
    if (e < E) atomicAdd(&deg[dst[e]], 1);
}

// exclusive scan, step 1: per-block scan of deg -> off(partial), block sums
__global__ void scan1_kernel(const int* __restrict__ deg, int* __restrict__ off,
                             int* __restrict__ bsums, int N) {
    __shared__ int s[256];
    const int tid = threadIdx.x;
    const int i = blockIdx.x * 256 + tid;
    const int v = (i < N) ? deg[i] : 0;
    s[tid] = v;
    __syncthreads();
    for (int o = 1; o < 256; o <<= 1) {
        int t = (tid >= o) ? s[tid - o] : 0;
        __syncthreads();
        s[tid] += t;
        __syncthreads();
    }
    if (i < N) off[i] = s[tid] - v;            // exclusive within block
    if (tid == 255) bsums[blockIdx.x] = s[255];
}

// step 2: exclusive scan of block sums (NB <= 256)
__global__ void scan2_kernel(int* __restrict__ bsums, int NB) {
    __shared__ int s[256];
    const int tid = threadIdx.x;
    const int v = (tid < NB) ? bsums[tid] : 0;
    s[tid] = v;
    __syncthreads();
    for (int o = 1; o < 256; o <<= 1) {
        int t = (tid >= o) ? s[tid - o] : 0;
        __syncthreads();
        s[tid] += t;
        __syncthreads();
    }
    if (tid < NB) bsums[tid] = s[tid] - v;
}

// step 3: off[i] += bsums[block]; cursor = off; off[N] = E; dis = rsqrt(deg+1)
__global__ void scan3_kernel(int* __restrict__ off, const int* __restrict__ bsums,
                             int* __restrict__ cursor, const int* __restrict__ deg,
                             float* __restrict__ dis, int N, int E) {
    const int i = blockIdx.x * 256 + threadIdx.x;
    if (i < N) {
        const int o = off[i] + bsums[blockIdx.x];
        off[i] = o;
        cursor[i] = o;
        dis[i] = rsqrtf((float)deg[i] + 1.0f);
    }
    if (i == 0) off[N] = E;
}

__global__ void fill_csr_kernel(const int* __restrict__ src, const int* __restrict__ dst,
                                int* __restrict__ cursor, int* __restrict__ csr_src, int E) {
    int e = blockIdx.x * blockDim.x + threadIdx.x;
    if (e < E) {
        const int pos = atomicAdd(&cursor[dst[e]], 1);
        csr_src[pos] = src[e];
    }
}

// ---- dense: h[n][c] = dis[n] * sum_k x[n][k] * W[k][c] ---------------------

template <int K, int C>
__global__ void gemm_scale_kernel(const float* __restrict__ x, const float* __restrict__ W,
                                  const float* __restrict__ dis, float* __restrict__ h, int N) {
    constexpr int NPB = 256 / C;                 // nodes per block
    __shared__ float xs[NPB][K];
    const int local = threadIdx.x / C;
    const int c     = threadIdx.x % C;
    const int node  = blockIdx.x * NPB + local;

    for (int i = threadIdx.x; i < NPB * K; i += 256) {
        const int ln = i / K, kk = i % K;
        const int nn = blockIdx.x * NPB + ln;
        xs[ln][kk] = (nn < N) ? x[(size_t)nn * K + kk] : 0.0f;
    }
    __syncthreads();
    if (node >= N) return;

    float acc = 0.0f;
#pragma unroll 8
    for (int k = 0; k < K; ++k) acc = fmaf(xs[local][k], W[k * C + c], acc);
    h[(size_t)node * C + c] = acc * dis[node];
}

// ---- aggregate (gather) + self-loop + scale + bias + ReLU, fused ----------
// group of C/4 lanes per destination node; each lane owns a float4 of channels
template <int C>
__global__ void gather_kernel(const float* __restrict__ h, const int* __restrict__ off,
                              const int* __restrict__ csr_src, const float* __restrict__ dis,
                              const float* __restrict__ b, float* __restrict__ out, int N) {
    constexpr int CQ = C / 4;
    const long long tid = (long long)blockIdx.x * blockDim.x + threadIdx.x;
    const int node = (int)(tid / CQ);
    const int q    = (int)(tid % CQ);
    if (node >= N) return;

    const int beg = off[node];
    const int end = off[node + 1];

    // self-loop contribution
    float4 acc = *reinterpret_cast<const float4*>(&h[(size_t)node * C + q * 4]);
    for (int i = beg; i < end; ++i) {
        const int s = csr_src[i];                 // broadcast within group
        const float4 v = *reinterpret_cast<const float4*>(&h[(size_t)s * C + q * 4]);
        acc.x += v.x; acc.y += v.y; acc.z += v.z; acc.w += v.w;
    }
    const float d = dis[node];
    float4 r;
    r.x = fmaf(acc.x, d, b[q * 4 + 0]);
    r.y = fmaf(acc.y, d, b[q * 4 + 1]);
    r.z = fmaf(acc.z, d, b[q * 4 + 2]);
    r.w = fmaf(acc.w, d, b[q * 4 + 3]);
    r.x = r.x > 0.0f ? r.x : 0.0f;
    r.y = r.y > 0.0f ? r.y : 0.0f;
    r.z = r.z > 0.0f ? r.z : 0.0f;
    r.w = r.w > 0.0f ? r.w : 0.0f;
    *reinterpret_cast<float4*>(&out[(size_t)node * C + q * 4]) = r;
}

// ---- pooling + head --------------------------------------------------------

__global__ void counts_kernel(const int* __restrict__ batch, float* __restrict__ counts, int N) {
    int n = blockIdx.x * blockDim.x + threadIdx.x;
    if (n < N) atomicAdd(&counts[batch[n]], 1.0f);
}

__global__ void pool_kernel(const float* __restrict__ x3, const int* __restrict__ batch,
                            float* __restrict__ pooled, int N) {
    const long long tid = (long long)blockIdx.x * blockDim.x + threadIdx.x;
    if (tid >= (long long)N * 32) return;
    const int n = (int)(tid / 32);
    const int c = (int)(tid % 32);
    atomicAdd(&pooled[batch[n] * 32 + c], x3[tid]);
}

__global__ void head_kernel(const float* __restrict__ pooled, const float* __restrict__ counts,
                            const float* __restrict__ Wl, const float* __restrict__ bl,
                            float* __restrict__ out) {
    __shared__ float p[32];
    const int g = blockIdx.x;
    if (threadIdx.x < 32) {
        float cnt = counts[g];
        cnt = cnt < 1.0f ? 1.0f : cnt;
        p[threadIdx.x] = pooled[g * 32 + threadIdx.x] / cnt;
    }
    __syncthreads();
    const int j = threadIdx.x;  // blockDim.x == 768
    float acc = bl[j];
#pragma unroll
    for (int k = 0; k < 32; ++k) acc = fmaf(p[k], Wl[k * 768 + j], acc);
    out[g * 768 + j] = acc;
}

// ---------------------------------------------------------------------------

extern "C" void kernel_launch(void* const* d_in, const int* in_sizes, int n_in,
                              void* d_out, int out_size, void* d_ws, size_t ws_size,
                              hipStream_t stream) {
    const float* x   = (const float*)d_in[0];
    const float* W1  = (const float*)d_in[1];
    const float* b1  = (const float*)d_in[2];
    const float* W2  = (const float*)d_in[3];
    const float* b2  = (const float*)d_in[4];
    const float* W3  = (const float*)d_in[5];
    const float* b3  = (const float*)d_in[6];
    const float* Wl  = (const float*)d_in[7];
    const float* bl  = (const float*)d_in[8];
    const int* ei    = (const int*)d_in[9];
    const int* batch = (const int*)d_in[10];

    const int N = in_sizes[0] / 128;    // 40000
    const int E = in_sizes[9] / 2;      // 640000
    const int G = out_size / 768;       // 256
    const int NB = (N + 255) / 256;     // scan blocks (<= 256 required)

    const int* src = ei;
    const int* dst = ei + E;
    float* out = (float*)d_out;

    // Workspace layout:
    //  floats: H[N*128] | A[N*128] | B[N*64] | dis[N] | pooled[G*32] | counts[G]
    //  ints:   deg[N] | off[N+1] | cursor[N] | bsums[256] | csr_src[E]
    float* H      = (float*)d_ws;
    float* A      = H + (size_t)N * 128;
    float* Bb     = A + (size_t)N * 128;
    float* dis    = Bb + (size_t)N * 64;
    float* pooled = dis + N;
    float* counts = pooled + (size_t)G * 32;
    int* deg      = (int*)(counts + G);
    int* off      = deg + N;
    int* cursor   = off + (N + 1);
    int* bsums    = cursor + N;
    int* csr_src  = bsums + 256;

    // ---- CSR build (every launch; ws is re-poisoned) ----
    hipMemsetAsync(deg, 0, (size_t)N * sizeof(int), stream);
    hipMemsetAsync(pooled, 0, ((size_t)G * 32 + G) * sizeof(float), stream);
    deg_count_kernel<<<(E + 255) / 256, 256, 0, stream>>>(dst, deg, E);
    scan1_kernel<<<NB, 256, 0, stream>>>(deg, off, bsums, N);
    scan2_kernel<<<1, 256, 0, stream>>>(bsums, NB);
    scan3_kernel<<<NB, 256, 0, stream>>>(off, bsums, cursor, deg, dis, N, E);
    fill_csr_kernel<<<(E + 255) / 256, 256, 0, stream>>>(src, dst, cursor, csr_src, E);

    // ---- Layer 1: 128 -> 128 : x -> A
    gemm_scale_kernel<128, 128><<<(N + 1) / 2, 256, 0, stream>>>(x, W1, dis, H, N);
    gather_kernel<128><<<(int)(((long long)N * 32 + 255) / 256), 256, 0, stream>>>(
        H, off, csr_src, dis, b1, A, N);

    // ---- Layer 2: 128 -> 64 : A -> B
    gemm_scale_kernel<128, 64><<<(N + 3) / 4, 256, 0, stream>>>(A, W2, dis, H, N);
    gather_kernel<64><<<(int)(((long long)N * 16 + 255) / 256), 256, 0, stream>>>(
        H, off, csr_src, dis, b2, Bb, N);

    // ---- Layer 3: 64 -> 32 : B -> A (reuse)
    gemm_scale_kernel<64, 32><<<(N + 7) / 8, 256, 0, stream>>>(Bb, W3, dis, H, N);
    gather_kernel<32><<<(int)(((long long)N * 8 + 255) / 256), 256, 0, stream>>>(
        H, off, csr_src, dis, b3, A, N);

    // ---- Global mean pool + head
    counts_kernel<<<(N + 255) / 256, 256, 0, stream>>>(batch, counts, N);
    pool_kernel<<<(int)(((long long)N * 32 + 255) / 256), 256, 0, stream>>>(A, batch, pooled, N);
    head_kernel<<<G, 768, 0, stream>>>(pooled, counts, Wl, bl, out);
}

// Round 3
// 383.492 us; speedup vs baseline: 5.9080x; 1.2678x over previous
//
#include <hip/hip_runtime.h>

// ---------------------------------------------------------------------------
// TorsoGCNv1: 3x GCNConv(+ReLU) -> global mean pool -> Linear head
// Round 3: register-blocked GEMM (W in LDS), run-length pool, unrolled gather.
// ---------------------------------------------------------------------------

// ---- CSR build -------------------------------------------------------------

__global__ void deg_count_kernel(const int* __restrict__ dst, int* __restrict__ deg, int E) {
    int e = blockIdx.x * blockDim.x + threadIdx.x;
    if (e < E) atomicAdd(&deg[dst[e]], 1);
}

__global__ void scan1_kernel(const int* __restrict__ deg, int* __restrict__ off,
                             int* __restrict__ bsums, int N) {
    __shared__ int s[256];
    const int tid = threadIdx.x;
    const int i = blockIdx.x * 256 + tid;
    const int v = (i < N) ? deg[i] : 0;
    s[tid] = v;
    __syncthreads();
    for (int o = 1; o < 256; o <<= 1) {
        int t = (tid >= o) ? s[tid - o] : 0;
        __syncthreads();
        s[tid] += t;
        __syncthreads();
    }
    if (i < N) off[i] = s[tid] - v;            // exclusive within block
    if (tid == 255) bsums[blockIdx.x] = s[255];
}

__global__ void scan2_kernel(int* __restrict__ bsums, int NB) {
    __shared__ int s[256];
    const int tid = threadIdx.x;
    const int v = (tid < NB) ? bsums[tid] : 0;
    s[tid] = v;
    __syncthreads();
    for (int o = 1; o < 256; o <<= 1) {
        int t = (tid >= o) ? s[tid - o] : 0;
        __syncthreads();
        s[tid] += t;
        __syncthreads();
    }
    if (tid < NB) bsums[tid] = s[tid] - v;
}

__global__ void scan3_kernel(int* __restrict__ off, const int* __restrict__ bsums,
                             int* __restrict__ cursor, const int* __restrict__ deg,
                             float* __restrict__ dis, int N, int E) {
    const int i = blockIdx.x * 256 + threadIdx.x;
    if (i < N) {
        const int o = off[i] + bsums[blockIdx.x];
        off[i] = o;
        cursor[i] = o;
        dis[i] = rsqrtf((float)deg[i] + 1.0f);
    }
    if (i == 0) off[N] = E;
}

__global__ void fill_csr_kernel(const int* __restrict__ src, const int* __restrict__ dst,
                                int* __restrict__ cursor, int* __restrict__ csr_src, int E) {
    int e = blockIdx.x * blockDim.x + threadIdx.x;
    if (e < E) {
        const int pos = atomicAdd(&cursor[dst[e]], 1);
        csr_src[pos] = src[e];
    }
}

// ---- dense: h[n][c] = dis[n] * sum_k x[n][k] * W[k][c] ---------------------
// W staged in LDS; each thread computes NR nodes x 8 channels in registers.
template <int K, int C, int NR>
__global__ __launch_bounds__(256) void gemm_scale_kernel(
        const float* __restrict__ x, const float* __restrict__ W,
        const float* __restrict__ dis, float* __restrict__ h, int N) {
    constexpr int TC  = C / 8;        // threads along c
    constexpr int TN  = 256 / TC;     // threads along n
    constexpr int NPB = NR * TN;      // nodes per block
    __shared__ float Ws[K * C];

    for (int i = threadIdx.x * 4; i < K * C; i += 256 * 4)
        *reinterpret_cast<float4*>(&Ws[i]) = *reinterpret_cast<const float4*>(W + i);
    __syncthreads();

    const int tc = threadIdx.x % TC;
    const int tn = threadIdx.x / TC;
    const int c0 = tc * 8;
    const int n0 = blockIdx.x * NPB + tn * NR;

    float acc[NR][8] = {};
    for (int k = 0; k < K; k += 4) {
        float4 xv[NR];
#pragma unroll
        for (int i = 0; i < NR; ++i) {
            const int nn = n0 + i;
            xv[i] = (nn < N) ? *reinterpret_cast<const float4*>(&x[(size_t)nn * K + k])
                             : float4{0.f, 0.f, 0.f, 0.f};
        }
#pragma unroll
        for (int kk = 0; kk < 4; ++kk) {
            float wv[8];
#pragma unroll
            for (int j = 0; j < 8; ++j) wv[j] = Ws[(k + kk) * C + c0 + j];
#pragma unroll
            for (int i = 0; i < NR; ++i) {
                const float xs = (&xv[i].x)[kk];
#pragma unroll
                for (int j = 0; j < 8; ++j) acc[i][j] = fmaf(xs, wv[j], acc[i][j]);
            }
        }
    }
#pragma unroll
    for (int i = 0; i < NR; ++i) {
        const int nn = n0 + i;
        if (nn < N) {
            const float d = dis[nn];
#pragma unroll
            for (int j = 0; j < 8; j += 4) {
                float4 r = { acc[i][j] * d, acc[i][j + 1] * d, acc[i][j + 2] * d, acc[i][j + 3] * d };
                *reinterpret_cast<float4*>(&h[(size_t)nn * C + c0 + j]) = r;
            }
        }
    }
}

// ---- aggregate (gather) + self-loop + scale + bias + ReLU, fused ----------
template <int C>
__global__ void gather_kernel(const float* __restrict__ h, const int* __restrict__ off,
                              const int* __restrict__ csr_src, const float* __restrict__ dis,
                              const float* __restrict__ b, float* __restrict__ out, int N) {
    constexpr int CQ = C / 4;
    const long long tid = (long long)blockIdx.x * blockDim.x + threadIdx.x;
    const int node = (int)(tid / CQ);
    const int q    = (int)(tid % CQ);
    if (node >= N) return;

    const int beg = off[node];
    const int end = off[node + 1];

    float4 acc = *reinterpret_cast<const float4*>(&h[(size_t)node * C + q * 4]);  // self loop
    int i = beg;
    for (; i + 2 <= end; i += 2) {
        const int s0 = csr_src[i];
        const int s1 = csr_src[i + 1];
        const float4 v0 = *reinterpret_cast<const float4*>(&h[(size_t)s0 * C + q * 4]);
        const float4 v1 = *reinterpret_cast<const float4*>(&h[(size_t)s1 * C + q * 4]);
        acc.x += v0.x + v1.x; acc.y += v0.y + v1.y;
        acc.z += v0.z + v1.z; acc.w += v0.w + v1.w;
    }
    if (i < end) {
        const int s = csr_src[i];
        const float4 v = *reinterpret_cast<const float4*>(&h[(size_t)s * C + q * 4]);
        acc.x += v.x; acc.y += v.y; acc.z += v.z; acc.w += v.w;
    }
    const float d = dis[node];
    float4 r;
    r.x = fmaf(acc.x, d, b[q * 4 + 0]);
    r.y = fmaf(acc.y, d, b[q * 4 + 1]);
    r.z = fmaf(acc.z, d, b[q * 4 + 2]);
    r.w = fmaf(acc.w, d, b[q * 4 + 3]);
    r.x = r.x > 0.0f ? r.x : 0.0f;
    r.y = r.y > 0.0f ? r.y : 0.0f;
    r.z = r.z > 0.0f ? r.z : 0.0f;
    r.w = r.w > 0.0f ? r.w : 0.0f;
    *reinterpret_cast<float4*>(&out[(size_t)node * C + q * 4]) = r;
}

// ---- pooling (run-length, batch sorted) + head -----------------------------
// thread owns channel ch and node range [n0, n0+8); one atomic per batch-run.
__global__ void pool_kernel(const float* __restrict__ x3, const int* __restrict__ batch,
                            float* __restrict__ pooled, float* __restrict__ counts, int N) {
    const long long tid = (long long)blockIdx.x * blockDim.x + threadIdx.x;
    const int ch = (int)(tid % 32);
    int n = (int)(tid / 32) * 8;
    if (n >= N) return;
    const int nEnd = (n + 8 < N) ? n + 8 : N;
    int g = batch[n];
    float acc = 0.0f, cnt = 0.0f;
    for (; n < nEnd; ++n) {
        const int gn = batch[n];
        if (gn != g) {
            atomicAdd(&pooled[g * 32 + ch], acc);
            if (ch == 0) atomicAdd(&counts[g], cnt);
            acc = 0.0f; cnt = 0.0f; g = gn;
        }
        acc += x3[(size_t)n * 32 + ch];
        cnt += 1.0f;
    }
    atomicAdd(&pooled[g * 32 + ch], acc);
    if (ch == 0) atomicAdd(&counts[g], cnt);
}

__global__ void head_kernel(const float* __restrict__ pooled, const float* __restrict__ counts,
                            const float* __restrict__ Wl, const float* __restrict__ bl,
                            float* __restrict__ out) {
    __shared__ float p[32];
    const int g = blockIdx.x;
    if (threadIdx.x < 32) {
        float cnt = counts[g];
        cnt = cnt < 1.0f ? 1.0f : cnt;
        p[threadIdx.x] = pooled[g * 32 + threadIdx.x] / cnt;
    }
    __syncthreads();
    const int j = threadIdx.x;  // blockDim.x == 768
    float acc = bl[j];
#pragma unroll
    for (int k = 0; k < 32; ++k) acc = fmaf(p[k], Wl[k * 768 + j], acc);
    out[g * 768 + j] = acc;
}

// ---------------------------------------------------------------------------

extern "C" void kernel_launch(void* const* d_in, const int* in_sizes, int n_in,
                              void* d_out, int out_size, void* d_ws, size_t ws_size,
                              hipStream_t stream) {
    const float* x   = (const float*)d_in[0];
    const float* W1  = (const float*)d_in[1];
    const float* b1  = (const float*)d_in[2];
    const float* W2  = (const float*)d_in[3];
    const float* b2  = (const float*)d_in[4];
    const float* W3  = (const float*)d_in[5];
    const float* b3  = (const float*)d_in[6];
    const float* Wl  = (const float*)d_in[7];
    const float* bl  = (const float*)d_in[8];
    const int* ei    = (const int*)d_in[9];
    const int* batch = (const int*)d_in[10];

    const int N = in_sizes[0] / 128;    // 40000
    const int E = in_sizes[9] / 2;      // 640000
    const int G = out_size / 768;       // 256
    const int NB = (N + 255) / 256;     // scan blocks (<= 256 required)

    const int* src = ei;
    const int* dst = ei + E;
    float* out = (float*)d_out;

    // Workspace:
    //  floats: H[N*128] | A[N*128] | B[N*64] | dis[N] | pooled[G*32] | counts[G]
    //  ints:   deg[N] | off[N+1] | cursor[N] | bsums[256] | csr_src[E]
    float* H      = (float*)d_ws;
    float* A      = H + (size_t)N * 128;
    float* Bb     = A + (size_t)N * 128;
    float* dis    = Bb + (size_t)N * 64;
    float* pooled = dis + N;
    float* counts = pooled + (size_t)G * 32;
    int* deg      = (int*)(counts + G);
    int* off      = deg + N;
    int* cursor   = off + (N + 1);
    int* bsums    = cursor + N;
    int* csr_src  = bsums + 256;

    // ---- CSR build (every launch; ws is re-poisoned) ----
    hipMemsetAsync(deg, 0, (size_t)N * sizeof(int), stream);
    hipMemsetAsync(pooled, 0, ((size_t)G * 32 + G) * sizeof(float), stream);
    deg_count_kernel<<<(E + 255) / 256, 256, 0, stream>>>(dst, deg, E);
    scan1_kernel<<<NB, 256, 0, stream>>>(deg, off, bsums, N);
    scan2_kernel<<<1, 256, 0, stream>>>(bsums, NB);
    scan3_kernel<<<NB, 256, 0, stream>>>(off, bsums, cursor, deg, dis, N, E);
    fill_csr_kernel<<<(E + 255) / 256, 256, 0, stream>>>(src, dst, cursor, csr_src, E);

    // ---- Layer 1: 128 -> 128 : x -> A   (NPB = 4*16 = 64 nodes/block)
    gemm_scale_kernel<128, 128, 4><<<(N + 63) / 64, 256, 0, stream>>>(x, W1, dis, H, N);
    gather_kernel<128><<<(int)(((long long)N * 32 + 255) / 256), 256, 0, stream>>>(
        H, off, csr_src, dis, b1, A, N);

    // ---- Layer 2: 128 -> 64 : A -> B    (NPB = 2*32 = 64 nodes/block)
    gemm_scale_kernel<128, 64, 2><<<(N + 63) / 64, 256, 0, stream>>>(A, W2, dis, H, N);
    gather_kernel<64><<<(int)(((long long)N * 16 + 255) / 256), 256, 0, stream>>>(
        H, off, csr_src, dis, b2, Bb, N);

    // ---- Layer 3: 64 -> 32 : B -> A     (NPB = 2*64 = 128 nodes/block)
    gemm_scale_kernel<64, 32, 2><<<(N + 127) / 128, 256, 0, stream>>>(Bb, W3, dis, H, N);
    gather_kernel<32><<<(int)(((long long)N * 8 + 255) / 256), 256, 0, stream>>>(
        H, off, csr_src, dis, b3, A, N);

    // ---- Global mean pool + head
    pool_kernel<<<(int)(((long long)((N + 7) / 8) * 32 + 255) / 256), 256, 0, stream>>>(
        A, batch, pooled, counts, N);
    head_kernel<<<G, 768, 0, stream>>>(pooled, counts, Wl, bl, out);
}